// Round 4
// baseline (52.510 us; speedup 1.0000x reference)
//
#include <hip/hip_runtime.h>

typedef _Float16 h2 __attribute__((ext_vector_type(2)));
typedef _Float16 h8 __attribute__((ext_vector_type(8)));

#define RANK  16
#define GRIDP 128
#define BLOCK 256
#define NBLK  4096

union H8 { h8 v; h2 p[4]; };

__device__ __forceinline__ float fdot2(h2 a, h2 b, float c) {
#if __has_builtin(__builtin_amdgcn_fdot2)
    return __builtin_amdgcn_fdot2(a, b, c, false);
#else
    return (float)a.x * (float)b.x + (float)a.y * (float)b.y + c;
#endif
}

// Build chunked f16 table in workspace: gt[a][c][g] = ranks 8c..8c+7 at grid g,
// 16B per entry. Only the c=1 chunk is gathered from global; c=0 lives in LDS.
__global__ void pinn_prep_kernel(const float* __restrict__ line,
                                 _Float16* __restrict__ gt) {
    int i = threadIdx.x + blockIdx.x * blockDim.x;
    if (i < 3 * RANK * GRIDP) {
        int a = i >> 11;          // / (16*128)
        int r = (i >> 7) & 15;    // rank
        int g = i & 127;          // grid row
        int c = r >> 3;           // rank half
        gt[((((a << 1) + c) << 7) + g) * 8 + (r & 7)] = (_Float16)line[i];
    }
}

__global__ __launch_bounds__(BLOCK, 4) void pinn_lora_kernel(
    const float* __restrict__ x, const float* __restrict__ line,
    const float* __restrict__ W, const h8* __restrict__ gt8,
    float* __restrict__ out, int npts)
{
    // LDS holds only ranks 0..7 (6 KiB): tab[a][g], 16B entries, class = g&7.
    __shared__ h8 tab[3][GRIDP];

    _Float16* t = (_Float16*)tab;
    for (int i = threadIdx.x; i < 3 * 8 * GRIDP; i += BLOCK) {
        int a = i >> 10;          // / (8*128)
        int r = (i >> 7) & 7;     // rank 0..7
        int g = i & 127;
        t[(((a << 7) + g) << 3) + r] = (_Float16)line[(a << 11) + (r << 7) + g];
    }

    // W[3][16] f32 -> packed f16 (uniform scalar loads)
    h2 Wp[3][8];
#pragma unroll
    for (int o = 0; o < 3; ++o)
#pragma unroll
        for (int d = 0; d < 8; ++d) {
            Wp[o][d].x = (_Float16)W[o * 16 + 2 * d];
            Wp[o][d].y = (_Float16)W[o * 16 + 2 * d + 1];
        }

    __syncthreads();

    int tid    = blockIdx.x * BLOCK + threadIdx.x;
    int stride = gridDim.x * BLOCK;

    for (int p = tid; p < npts; p += stride) {
        // streaming I/O: nontemporal so it doesn't evict the table from L1
        float cx = __builtin_nontemporal_load(x + 3 * p + 0);
        float cy = __builtin_nontemporal_load(x + 3 * p + 1);
        float cz = __builtin_nontemporal_load(x + 3 * p + 2);
        float crd[3] = {cz, cy, cx};   // axis a interpolates x[:, 2-a]

        int idx[3];
        h2  wv[3];
#pragma unroll
        for (int a = 0; a < 3; ++a) {
            float pos = fmaf(crd[a], 63.5f, 63.5f);
            int   i0  = (int)pos;              // pos >= 0 -> trunc == floor
            i0 = (i0 > 126) ? 126 : i0;
            float w = pos - (float)i0;
            _Float16 wh = (_Float16)w;
            h2 w2; w2.x = wh; w2.y = wh;
            idx[a] = i0;
            wv[a]  = w2;
        }

        // issue the 6 global gathers (ranks 8..15, L1-resident) early
        H8 A1[3], B1[3];
#pragma unroll
        for (int a = 0; a < 3; ++a) {
            const h8* base = gt8 + (((a << 1) | 1) << 7);
            A1[a].v = base[idx[a]];
            B1[a].v = base[idx[a] + 1];
        }

        // ranks 0..7 via LDS while the global loads are in flight
        H8 prod0;
#pragma unroll
        for (int a = 0; a < 3; ++a) {
            H8 A0, B0;
            A0.v = tab[a][idx[a]];
            B0.v = tab[a][idx[a] + 1];
            H8 v0;
#pragma unroll
            for (int j = 0; j < 4; ++j)
                v0.p[j] = A0.p[j] + (B0.p[j] - A0.p[j]) * wv[a];
            if (a == 0) prod0 = v0;
            else {
#pragma unroll
                for (int j = 0; j < 4; ++j) prod0.p[j] *= v0.p[j];
            }
        }

        // ranks 8..15 from the global gathers
        H8 prod1;
#pragma unroll
        for (int a = 0; a < 3; ++a) {
            H8 v1;
#pragma unroll
            for (int j = 0; j < 4; ++j)
                v1.p[j] = A1[a].p[j] + (B1[a].p[j] - A1[a].p[j]) * wv[a];
            if (a == 0) prod1 = v1;
            else {
#pragma unroll
                for (int j = 0; j < 4; ++j) prod1.p[j] *= v1.p[j];
            }
        }

#pragma unroll
        for (int oo = 0; oo < 3; ++oo) {
            float acc = 0.f;
#pragma unroll
            for (int j = 0; j < 4; ++j) {
                acc = fdot2(prod0.p[j], Wp[oo][j],     acc);
                acc = fdot2(prod1.p[j], Wp[oo][j + 4], acc);
            }
            __builtin_nontemporal_store(acc, out + 3 * p + oo);
        }
    }
}

extern "C" void kernel_launch(void* const* d_in, const int* in_sizes, int n_in,
                              void* d_out, int out_size, void* d_ws, size_t ws_size,
                              hipStream_t stream) {
    const float* x    = (const float*)d_in[0];   // [N,3] f32
    const float* line = (const float*)d_in[1];   // [3,16,128] f32
    const float* W    = (const float*)d_in[2];   // [3,16] f32
    float*       out  = (float*)d_out;           // [N,3] f32
    _Float16*    gt   = (_Float16*)d_ws;         // 3*16*128 f16 = 12 KiB

    int npts = in_sizes[0] / 3;

    pinn_prep_kernel<<<(3 * RANK * GRIDP + BLOCK - 1) / BLOCK, BLOCK, 0, stream>>>(line, gt);
    pinn_lora_kernel<<<NBLK, BLOCK, 0, stream>>>(x, line, W, (const h8*)gt, out, npts);
}

// Round 5
// 38.334 us; speedup vs baseline: 1.3698x; 1.3698x over previous
//
#include <hip/hip_runtime.h>

typedef _Float16 h2 __attribute__((ext_vector_type(2)));
typedef _Float16 h8 __attribute__((ext_vector_type(8)));

#define RANK  16
#define GRIDP 128
#define BLOCK 256
#define NBLK  4096

union H8 { h8 v; h2 p[4]; };

struct F3 { float a, b, c; };   // 12-byte packed, 4B aligned -> dwordx3

__device__ __forceinline__ float fdot2(h2 a, h2 b, float c) {
#if __has_builtin(__builtin_amdgcn_fdot2)
    return __builtin_amdgcn_fdot2(a, b, c, false);
#else
    return (float)a.x * (float)b.x + (float)a.y * (float)b.y + c;
#endif
}

// sum over lane pair {l, l^1} via DPP quad_perm [1,0,3,2] -- VALU pipe, no LDS
__device__ __forceinline__ float pair_sum(float v) {
    int o = __builtin_amdgcn_mov_dpp(__float_as_int(v), 0xB1, 0xF, 0xF, true);
    return v + __int_as_float(o);
}

__global__ __launch_bounds__(BLOCK) void pinn_lora_kernel(
    const float* __restrict__ x, const float* __restrict__ line,
    const float* __restrict__ W, float* __restrict__ out, int npts)
{
    // Chunked fp16 table: tab[a][c][g] = ranks 8c..8c+7 of grid row g (16B).
    // Lane pair (2q,2q+1) reads chunks c=0,1 of the SAME row -> only 32
    // distinct random rows per wave gather (2-way pair aliasing is free).
    __shared__ h8 tab[3][2][GRIDP];

    _Float16* t = (_Float16*)tab;
    for (int i = threadIdx.x; i < 3 * RANK * GRIDP; i += BLOCK) {
        int a = i >> 11;          // / (16*128)
        int r = (i >> 7) & 15;    // rank
        int g = i & 127;          // grid row
        int c = r >> 3;           // rank half
        t[((((a << 1) + c) << 7) + g) * 8 + (r & 7)] = (_Float16)line[i];
    }

    // W[3][16] f32 -> packed f16, then parity-select this lane's rank half.
    // All indexing compile-time constant (no scratch).
    const int c = threadIdx.x & 1;
    h2 Ws[3][4];
#pragma unroll
    for (int o = 0; o < 3; ++o)
#pragma unroll
        for (int d = 0; d < 4; ++d) {
            int r0 = (c ? 8 : 0) + 2 * d;
            h2 w;
            w.x = (_Float16)W[o * 16 + r0];
            w.y = (_Float16)W[o * 16 + r0 + 1];
            Ws[o][d] = w;
        }

    __syncthreads();

    int t0     = blockIdx.x * BLOCK + threadIdx.x;   // task id; task&1 == c
    int stride = gridDim.x * BLOCK;
    int ntask  = 2 * npts;

    for (int tk = t0; tk < ntask; tk += stride) {
        int p = tk >> 1;

        // both lanes of the pair load the same 12B (broadcast in L1)
        F3 cc = *(const F3*)(x + 3 * p);
        float crd[3] = {cc.c, cc.b, cc.a};   // axis a interpolates x[:, 2-a]

        H8 prod;
#pragma unroll
        for (int a = 0; a < 3; ++a) {
            float pos = fmaf(crd[a], 63.5f, 63.5f);
            int   i0  = (int)pos;              // pos >= 0 -> trunc == floor
            i0 = (i0 > 126) ? 126 : i0;
            float w = pos - (float)i0;
            _Float16 wh = (_Float16)w;
            h2 w2; w2.x = wh; w2.y = wh;

            H8 A, B;
            A.v = tab[a][c][i0];        // this lane's rank half, row i0
            B.v = tab[a][c][i0 + 1];    // row i0+1

            H8 v;
#pragma unroll
            for (int j = 0; j < 4; ++j)
                v.p[j] = A.p[j] + (B.p[j] - A.p[j]) * w2;

            if (a == 0) prod = v;
            else {
#pragma unroll
                for (int j = 0; j < 4; ++j) prod.p[j] *= v.p[j];
            }
        }

        float s[3];
#pragma unroll
        for (int oo = 0; oo < 3; ++oo) {
            float acc = 0.f;
#pragma unroll
            for (int j = 0; j < 4; ++j)
                acc = fdot2(prod.p[j], Ws[oo][j], acc);
            s[oo] = pair_sum(acc);      // ranks 0..7 + ranks 8..15
        }

        // both lanes hold all 3 outputs; split the store across the pair
        if (c == 0) {
            out[3 * p + 0] = s[0];
            out[3 * p + 1] = s[1];
        } else {
            out[3 * p + 2] = s[2];
        }
    }
}

extern "C" void kernel_launch(void* const* d_in, const int* in_sizes, int n_in,
                              void* d_out, int out_size, void* d_ws, size_t ws_size,
                              hipStream_t stream) {
    const float* x    = (const float*)d_in[0];   // [N,3] f32
    const float* line = (const float*)d_in[1];   // [3,16,128] f32
    const float* W    = (const float*)d_in[2];   // [3,16] f32
    float*       out  = (float*)d_out;           // [N,3] f32

    int npts = in_sizes[0] / 3;

    pinn_lora_kernel<<<NBLK, BLOCK, 0, stream>>>(x, line, W, out, npts);
}